// Round 1
// 4321.040 us; speedup vs baseline: 1.8792x; 1.8792x over previous
//
#include <hip/hip_runtime.h>
#include <math.h>

// ---------------------------------------------------------------------------
// Problem constants (ResonanceTransformer): B=16,S=512,D=512,F=2048,L=6,V=10000
// M = B*S = 8192 tokens.
// ---------------------------------------------------------------------------
#define MTOK   8192
#define DMODEL 512
#define DFF    2048
#define NLAYER 6
#define VOCAB  10000
#define VPAD   10112     // vocab padded to multiple of 128 for GEMM tiles
#define NHEAD  8
#define DHEAD  64

typedef __attribute__((ext_vector_type(8))) __bf16 bf16x8;
typedef __attribute__((ext_vector_type(4))) float  f32x4;

// ---------------------------------------------------------------------------
// ws layout (bytes) — total identical to previous passing kernel (105,448,720)
//   X   : fp32 [8192][512]   residual stream
//   Y   : fp32 [8192][512]   attn-out / ff2-out
//   SH  : 67 MB shared region: QKV fp32 [8192][1536] -> Z fp32 [8192][512]
//         -> F fp32 [8192][2048] -> vocab weight splits (2 x 10112x512 bf16)
//   WH/WL: per-layer weight splits, bf16 hi/lo, max 2048x512
// ---------------------------------------------------------------------------
static const size_t X_B     = 0;
static const size_t Y_B     = (size_t)MTOK * DMODEL * 4;                  // 16,777,216
static const size_t SH_B    = Y_B * 2;                                     // 33,554,432
static const size_t WH_B    = SH_B + (size_t)MTOK * DFF * 4;               // 100,663,296
static const size_t WL_B    = WH_B + (size_t)DFF * DMODEL * 2;             // 102,760,448
static const size_t HIST_B  = WL_B + (size_t)DFF * DMODEL * 2;             // 104,857,600
static const size_t STATE_B = HIST_B + (size_t)36 * 4096 * 4;              // 105,447,424
static const size_t THR_B   = STATE_B + (size_t)36 * 32;                   // 105,448,576
static const size_t WS_NEED = THR_B + 18 * 8;

struct PState {
    double lo, hi;
    unsigned int rank;
    unsigned int pad;
    unsigned long long found;   // f64 bits of captured order statistic
};

// ---------------------------------------------------------------------------
// bf16 split helpers (RTNE)
// ---------------------------------------------------------------------------
__device__ __forceinline__ unsigned short f2b(float f)
{
    unsigned int u = __float_as_uint(f);
    u += 0x7fffu + ((u >> 16) & 1u);
    return (unsigned short)(u >> 16);
}
__device__ __forceinline__ float b2f(unsigned short h)
{
    return __uint_as_float(((unsigned int)h) << 16);
}

__device__ __forceinline__ void gload16(const void* g, void* l)
{
    __builtin_amdgcn_global_load_lds(
        (const __attribute__((address_space(1))) unsigned int*)g,
        (__attribute__((address_space(3))) unsigned int*)l, 16, 0, 0);
}

// ---------------------------------------------------------------------------
// prune: |etched| chain (unchanged numerics)
// ---------------------------------------------------------------------------
__device__ __forceinline__ double etched_abs(float wv, int i, double step, double invn)
{
    float b0 = sinf(wv * 3.14159274f);
    b0 = fminf(1.0f, fmaxf(-1.0f, b0));
    double theta = step * (double)i;
    double c = cos(theta * invn + 2.0943951023931953);
    double bl = (double)b0;
    double bloom = bl + bl * c * 1.5;
    double e = cos(bloom * 9.869604401089358)
             + bloom * bloom * 0.003183098861837907;
    return fabs(e);
}

__device__ __forceinline__ void prune_matrix(int m, const float* ipw, const float* w1,
                                             const float* w2, const float** w, int* n)
{
    int l = m / 3, j = m % 3;
    if (j == 0)      { *w = ipw + (size_t)l * 786432;  *n = 786432;  }
    else if (j == 1) { *w = w1  + (size_t)l * 1048576; *n = 1048576; }
    else             { *w = w2  + (size_t)l * 1048576; *n = 1048576; }
}

__global__ __launch_bounds__(256) void k_prune_init(unsigned int* hist, PState* st)
{
    int gid = blockIdx.x * 256 + threadIdx.x;
    for (int i = gid; i < 36 * 4096; i += gridDim.x * 256) hist[i] = 0u;
    if (gid < 36) {
        int m = gid >> 1;
        int n = (m % 3 == 0) ? 786432 : 1048576;
        st[gid].lo = 0.0;
        st[gid].hi = 1.03;
        st[gid].rank = (unsigned)(n / 4 - 1 + (gid & 1));
        st[gid].found = 0x7FF0000000000000ULL;
    }
}

__global__ __launch_bounds__(256) void k_prune_hist(const float* ipw, const float* w1,
                                                    const float* w2, unsigned int* hist,
                                                    PState* st)
{
    int m = blockIdx.x >> 6;
    int chunk = blockIdx.x & 63;
    const float* w; int n;
    prune_matrix(m, ipw, w1, w2, &w, &n);
    __shared__ unsigned int h[2][4096];
    for (int i = threadIdx.x; i < 8192; i += 256) ((unsigned int*)h)[i] = 0u;
    __syncthreads();
    double lo0 = st[2*m].lo,   hi0 = st[2*m].hi;
    double lo1 = st[2*m+1].lo, hi1 = st[2*m+1].hi;
    double sc0 = 4096.0 / (hi0 - lo0);
    double sc1 = 4096.0 / (hi1 - lo1);
    double step = (double)n / (double)(n - 1);
    double invn = 1.0 / (double)n;
    int per = (n + 63) >> 6;
    int i0 = chunk * per;
    int i1 = min(n, i0 + per);
    for (int i = i0 + (int)threadIdx.x; i < i1; i += 256) {
        double a = etched_abs(w[i], i, step, invn);
        if (a >= lo0 && a < hi0) {
            int bin = (int)((a - lo0) * sc0); if (bin > 4095) bin = 4095;
            atomicAdd(&h[0][bin], 1u);
        }
        if (a >= lo1 && a < hi1) {
            int bin = (int)((a - lo1) * sc1); if (bin > 4095) bin = 4095;
            atomicAdd(&h[1][bin], 1u);
        }
    }
    __syncthreads();
    for (int i = threadIdx.x; i < 4096; i += 256) {
        if (h[0][i]) atomicAdd(&hist[(size_t)(2*m) * 4096 + i], h[0][i]);
        if (h[1][i]) atomicAdd(&hist[(size_t)(2*m+1) * 4096 + i], h[1][i]);
    }
}

__global__ __launch_bounds__(256) void k_prune_select(unsigned int* hist, PState* st)
{
    int s = blockIdx.x;
    __shared__ unsigned int h[4096];
    unsigned int* gh = hist + (size_t)s * 4096;
    for (int i = threadIdx.x; i < 4096; i += 256) { h[i] = gh[i]; gh[i] = 0u; }
    __syncthreads();
    if (threadIdx.x == 0) {
        PState ps = st[s];
        unsigned int r = ps.rank;
        unsigned int acc = 0;
        int bsel = -1; unsigned int newr = 0;
        for (int bi = 0; bi < 4096; ++bi) {
            unsigned int c = h[bi];
            if (bsel < 0 && r < acc + c) { bsel = bi; newr = r - acc; }
            acc += c;
        }
        if (bsel < 0) {
            for (int bi = 4095; bi >= 0; --bi)
                if (h[bi]) { bsel = bi; newr = h[bi] - 1; break; }
            if (bsel < 0) { bsel = 0; newr = 0; }
        }
        double width = (ps.hi - ps.lo) / 4096.0;
        st[s].lo = ps.lo + width * bsel;
        st[s].hi = ps.lo + width * (bsel + 1);
        st[s].rank = newr;
    }
}

__global__ __launch_bounds__(256) void k_prune_capture(const float* ipw, const float* w1,
                                                       const float* w2, PState* st)
{
    int m = blockIdx.x >> 6;
    int chunk = blockIdx.x & 63;
    const float* w; int n;
    prune_matrix(m, ipw, w1, w2, &w, &n);
    double lo0 = st[2*m].lo, lo1 = st[2*m+1].lo;
    double step = (double)n / (double)(n - 1);
    double invn = 1.0 / (double)n;
    unsigned long long mn0 = 0x7FF0000000000000ULL, mn1 = 0x7FF0000000000000ULL;
    int per = (n + 63) >> 6;
    int i0 = chunk * per;
    int i1 = min(n, i0 + per);
    for (int i = i0 + (int)threadIdx.x; i < i1; i += 256) {
        double a = etched_abs(w[i], i, step, invn);
        unsigned long long bits = (unsigned long long)__double_as_longlong(a);
        if (a >= lo0 && bits < mn0) mn0 = bits;
        if (a >= lo1 && bits < mn1) mn1 = bits;
    }
    __shared__ unsigned long long sm[2];
    if (threadIdx.x == 0) { sm[0] = 0x7FF0000000000000ULL; sm[1] = 0x7FF0000000000000ULL; }
    __syncthreads();
    atomicMin(&sm[0], mn0);
    atomicMin(&sm[1], mn1);
    __syncthreads();
    if (threadIdx.x == 0) {
        atomicMin(&st[2*m].found, sm[0]);
        atomicMin(&st[2*m+1].found, sm[1]);
    }
}

__global__ void k_prune_thr(PState* st, double* thr)
{
    int m = threadIdx.x;
    if (m < 18) {
        double v0 = __longlong_as_double((long long)st[2*m].found);
        double v1 = __longlong_as_double((long long)st[2*m+1].found);
        thr[m] = v0 + 0.75 * (v1 - v0);
    }
}

// mask + bf16 hi/lo split of a pruned weight matrix
__global__ __launch_bounds__(256) void k_apply_mask_split(const float* __restrict__ w,
                                                          unsigned short* __restrict__ oh,
                                                          unsigned short* __restrict__ ol,
                                                          const double* __restrict__ thr,
                                                          int m, int n)
{
    double T = thr[m];
    double step = (double)n / (double)(n - 1);
    double invn = 1.0 / (double)n;
    for (int i = blockIdx.x * 256 + threadIdx.x; i < n; i += gridDim.x * 256) {
        double a = etched_abs(w[i], i, step, invn);
        float v = (a > T) ? w[i] : 0.0f;
        unsigned short h = f2b(v);
        oh[i] = h;
        ol[i] = f2b(v - b2f(h));
    }
}

// plain bf16 hi/lo split (with zero padding past n, up to total)
__global__ __launch_bounds__(256) void k_split(const float* __restrict__ w,
                                               unsigned short* __restrict__ oh,
                                               unsigned short* __restrict__ ol,
                                               int n, int total)
{
    for (int i = blockIdx.x * 256 + threadIdx.x; i < total; i += gridDim.x * 256) {
        float v = (i < n) ? w[i] : 0.0f;
        unsigned short h = f2b(v);
        oh[i] = h;
        ol[i] = f2b(v - b2f(h));
    }
}

// ---------------------------------------------------------------------------
// embedding
// ---------------------------------------------------------------------------
__global__ __launch_bounds__(256) void k_embed(const int* __restrict__ src,
                                               const float* __restrict__ emb,
                                               const float* __restrict__ pos,
                                               float* __restrict__ x)
{
    int t = blockIdx.x;
    int tid = threadIdx.x;
    int v = src[t];
    int s = t & 511;
    const float* e = emb + (size_t)v * DMODEL;
    const float* p = pos + (size_t)s * DMODEL;
    float* xo = x + (size_t)t * DMODEL;
    xo[tid]       = e[tid]       * 22.627416997969522f + p[tid];
    xo[tid + 256] = e[tid + 256] * 22.627416997969522f + p[tid + 256];
}

// ---------------------------------------------------------------------------
// MFMA GEMM (bf16x3 split):  C[M,N] = A[M,K] @ B[N,K]^T + bias[N]  (opt relu)
//   A: fp32, split to bf16 hi/lo during LDS staging (reg-stage + ds_write)
//   B: pre-split bf16 hi/lo arrays [N][K] (N padded to x128 by caller)
// 128x128 tile, 4 waves (2x2 of 64x64), BK=32, mfma_f32_16x16x32_bf16.
// LDS XOR-swizzle: element (row,k) at byte row*64 + ((k>>3 ^ ((row>>1)&3))<<4)
//                  + (k&7)*2   -> fragment ds_read_b128 is 2-way (free).
// B staged with global_load_lds (linear LDS dest, pre-swizzled global source).
// ---------------------------------------------------------------------------
__global__ __launch_bounds__(256) void k_gemm_mfma(const float* __restrict__ A,
                                                   const unsigned short* __restrict__ BH,
                                                   const unsigned short* __restrict__ BL,
                                                   const float* __restrict__ bias,
                                                   float* __restrict__ C,
                                                   int M, int N, int K, int relu)
{
    __shared__ __align__(16) unsigned char LA[16384];   // AH | AL  (8 KB each)
    __shared__ __align__(16) unsigned char LB[16384];   // BH | BL
    unsigned char* LAH = LA;
    unsigned char* LAL = LA + 8192;
    unsigned char* LBH = LB;
    unsigned char* LBL = LB + 8192;

    const int t    = threadIdx.x;
    const int lane = t & 63;
    const int wv   = t >> 6;
    const int wm   = wv >> 1;        // wave row (0..1)
    const int wn   = wv & 1;         // wave col (0..1)
    const int rowBase = blockIdx.y * 128;
    const int colBase = blockIdx.x * 128;

    const f32x4 zero = {0.0f, 0.0f, 0.0f, 0.0f};
    f32x4 acc[4][4];
#pragma unroll
    for (int i = 0; i < 4; ++i)
#pragma unroll
        for (int j = 0; j < 4; ++j) acc[i][j] = zero;

    // swizzled fragment ds_read byte offsets
    int aoff[4], boff[4];
#pragma unroll
    for (int i = 0; i < 4; ++i) {
        int ra = (wm << 6) + (i << 4) + (lane & 15);
        aoff[i] = ra * 64 + (((lane >> 4) ^ ((ra >> 1) & 3)) << 4);
        int rb = (wn << 6) + (i << 4) + (lane & 15);
        boff[i] = rb * 64 + (((lane >> 4) ^ ((rb >> 1) & 3)) << 4);
    }

    for (int k0 = 0; k0 < K; k0 += 32) {
        // A: global fp32 loads (regs) — issued before barrier, hides under prev MFMA
        float4 av[4];
#pragma unroll
        for (int u = 0; u < 4; ++u) {
            int s = t + (u << 8);            // slot 0..1023: row = s>>3, k = (s&7)*4
            int r = s >> 3, kc = (s & 7) << 2;
            av[u] = *(const float4*)(A + (size_t)(rowBase + r) * K + (k0 + kc));
        }
        __syncthreads();                     // prev tile fully consumed

        // B: async global->LDS, linear dest + inverse-swizzled source
#pragma unroll
        for (int u = 0; u < 2; ++u) {
            int o = (wv << 10) + (u << 12) + (lane << 4);   // linear LDS byte
            int r = o >> 6;
            int cp = (o >> 4) & 3;
            int kk = (cp ^ ((r >> 1) & 3)) << 3;            // source k for this slot
            size_t g = (size_t)(colBase + r) * K + (k0 + kk);
            gload16(BH + g, LBH + (wv << 10) + (u << 12));
            gload16(BL + g, LBL + (wv << 10) + (u << 12));
        }

        // A: split to bf16 hi/lo, swizzled ds_write
#pragma unroll
        for (int u = 0; u < 4; ++u) {
            int s = t + (u << 8);
            int r = s >> 3;
            int kbyte = (s & 7) << 3;        // 0..56 (8B granules)
            int ad = r * 64 + ((((kbyte >> 4)) ^ ((r >> 1) & 3)) << 4) + (kbyte & 8);
            const float* a_ = &av[u].x;
            unsigned short hh[4], ll[4];
#pragma unroll
            for (int j = 0; j < 4; ++j) {
                hh[j] = f2b(a_[j]);
                ll[j] = f2b(a_[j] - b2f(hh[j]));
            }
            uint2 hv, lv;
            hv.x = (unsigned)hh[0] | ((unsigned)hh[1] << 16);
            hv.y = (unsigned)hh[2] | ((unsigned)hh[3] << 16);
            lv.x = (unsigned)ll[0] | ((unsigned)ll[1] << 16);
            lv.y = (unsigned)ll[2] | ((unsigned)ll[3] << 16);
            *(uint2*)(LAH + ad) = hv;
            *(uint2*)(LAL + ad) = lv;
        }
        __syncthreads();                     // staging complete (vmcnt+lgkm drained)

        bf16x8 ah[4], alo[4], bh[4], blo[4];
#pragma unroll
        for (int i = 0; i < 4; ++i) {
            ah[i]  = *(const bf16x8*)(LAH + aoff[i]);
            alo[i] = *(const bf16x8*)(LAL + aoff[i]);
            bh[i]  = *(const bf16x8*)(LBH + boff[i]);
            blo[i] = *(const bf16x8*)(LBL + boff[i]);
        }
#pragma unroll
        for (int i = 0; i < 4; ++i)
#pragma unroll
            for (int j = 0; j < 4; ++j) {
                acc[i][j] = __builtin_amdgcn_mfma_f32_16x16x32_bf16(alo[i], bh[j],  acc[i][j], 0, 0, 0);
                acc[i][j] = __builtin_amdgcn_mfma_f32_16x16x32_bf16(ah[i],  blo[j], acc[i][j], 0, 0, 0);
                acc[i][j] = __builtin_amdgcn_mfma_f32_16x16x32_bf16(ah[i],  bh[j],  acc[i][j], 0, 0, 0);
            }
    }

    // epilogue: C/D layout col=lane&15, row=(lane>>4)*4+reg
#pragma unroll
    for (int j = 0; j < 4; ++j) {
        int col = colBase + (wn << 6) + (j << 4) + (lane & 15);
        if (col < N) {
            float bv = bias[col];
#pragma unroll
            for (int i = 0; i < 4; ++i) {
                int row0 = rowBase + (wm << 6) + (i << 4) + ((lane >> 4) << 2);
#pragma unroll
                for (int r = 0; r < 4; ++r) {
                    float v = acc[i][j][r] + bv;
                    if (relu) v = fmaxf(v, 0.0f);
                    C[(size_t)(row0 + r) * N + col] = v;
                }
            }
        }
    }
}

// ---------------------------------------------------------------------------
// flash attention v2 (unchanged, fp32)
// ---------------------------------------------------------------------------
__global__ __launch_bounds__(256) void k_attn(const float* __restrict__ qkv,
                                              float* __restrict__ out)
{
    __shared__ float Qs[64][68];
    __shared__ float KP[64][68];
    __shared__ float Vs[64][64];
    __shared__ float red[64][17];
    __shared__ float mS[64], lS[64], aS[64];

    int bh = blockIdx.x;
    int b = bh >> 3, h = bh & 7;
    int qt = blockIdx.y;
    int t = threadIdx.x;
    int tx = t & 15, ty = t >> 4;
    int r0 = ty * 4, c0 = tx * 4;
    int rowq = b * 512 + qt * 64;

    size_t baseq = (size_t)rowq * 1536 + h * 64;
#pragma unroll
    for (int u = 0; u < 4; ++u) {
        int f = t + u * 256;
        int r = f >> 4;
        int d4 = (f & 15) << 2;
        float4 q4 = *(const float4*)(qkv + baseq + (size_t)r * 1536 + d4);
        Qs[d4 + 0][r] = q4.x; Qs[d4 + 1][r] = q4.y;
        Qs[d4 + 2][r] = q4.z; Qs[d4 + 3][r] = q4.w;
    }
    float O[4][4];
#pragma unroll
    for (int i = 0; i < 4; ++i)
#pragma unroll
        for (int j = 0; j < 4; ++j) O[i][j] = 0.0f;
    if (t < 64) { mS[t] = -INFINITY; lS[t] = 0.0f; }

    size_t basek = (size_t)(b * 512) * 1536 + h * 64;
    for (int kt = 0; kt < 8; ++kt) {
        __syncthreads();
#pragma unroll
        for (int u = 0; u < 4; ++u) {
            int f = t + u * 256;
            int r = f >> 4;
            int d4 = (f & 15) << 2;
            size_t g = basek + (size_t)(kt * 64 + r) * 1536 + d4;
            float4 k4 = *(const float4*)(qkv + g + 512);
            KP[d4 + 0][r] = k4.x; KP[d4 + 1][r] = k4.y;
            KP[d4 + 2][r] = k4.z; KP[d4 + 3][r] = k4.w;
            float4 v4 = *(const float4*)(qkv + g + 1024);
            *(float4*)&Vs[r][d4] = v4;
        }
        __syncthreads();
        float S[4][4];
#pragma unroll
        for (int i = 0; i < 4; ++i)
#pragma unroll
            for (int j = 0; j < 4; ++j) S[i][j] = 0.0f;
#pragma unroll 16
        for (int d = 0; d < 64; ++d) {
            float4 qa = *(const float4*)&Qs[d][r0];
            float4 kb = *(const float4*)&KP[d][c0];
            const float* qa_ = &qa.x;
            const float* kb_ = &kb.x;
#pragma unroll
            for (int i = 0; i < 4; ++i)
#pragma unroll
                for (int j = 0; j < 4; ++j)
                    S[i][j] = fmaf(qa_[i], kb_[j], S[i][j]);
        }
#pragma unroll
        for (int i = 0; i < 4; ++i) {
            float mx = fmaxf(fmaxf(S[i][0], S[i][1]), fmaxf(S[i][2], S[i][3]));
            red[r0 + i][tx] = mx * 0.125f;
        }
        __syncthreads();
        if (t < 64) {
            float m = red[t][0];
#pragma unroll
            for (int k = 1; k < 16; ++k) m = fmaxf(m, red[t][k]);
            float mo = mS[t];
            float mn = fmaxf(mo, m);
            aS[t] = __expf(mo - mn);
            mS[t] = mn;
        }
        __syncthreads();
#pragma unroll
        for (int i = 0; i < 4; ++i) {
            float mn = mS[r0 + i];
            float rs = 0.0f;
#pragma unroll
            for (int j = 0; j < 4; ++j) {
                float p = __expf(fmaf(S[i][j], 0.125f, -mn));
                S[i][j] = p;
                rs += p;
            }
            red[r0 + i][tx] = rs;
            *(float4*)&KP[r0 + i][c0] = *(float4*)S[i];
        }
        __syncthreads();
        if (t < 64) {
            float s = red[t][0];
#pragma unroll
            for (int k = 1; k < 16; ++k) s += red[t][k];
            lS[t] = lS[t] * aS[t] + s;
        }
        float pv[4][4];
#pragma unroll
        for (int i = 0; i < 4; ++i)
#pragma unroll
            for (int j = 0; j < 4; ++j) pv[i][j] = 0.0f;
#pragma unroll 4
        for (int c4 = 0; c4 < 64; c4 += 4) {
            float pr[4][4];
#pragma unroll
            for (int i = 0; i < 4; ++i)
                *(float4*)pr[i] = *(const float4*)&KP[r0 + i][c4];
#pragma unroll
            for (int cc = 0; cc < 4; ++cc) {
                float4 v = *(const float4*)&Vs[c4 + cc][c0];
                const float* v_ = &v.x;
#pragma unroll
                for (int i = 0; i < 4; ++i)
#pragma unroll
                    for (int j = 0; j < 4; ++j)
                        pv[i][j] = fmaf(pr[i][cc], v_[j], pv[i][j]);
            }
        }
#pragma unroll
        for (int i = 0; i < 4; ++i) {
            float a = aS[r0 + i];
#pragma unroll
            for (int j = 0; j < 4; ++j) O[i][j] = O[i][j] * a + pv[i][j];
        }
    }
    __syncthreads();
#pragma unroll
    for (int i = 0; i < 4; ++i) {
        float inv = 1.0f / lS[r0 + i];
        float4 o;
        o.x = O[i][0] * inv; o.y = O[i][1] * inv;
        o.z = O[i][2] * inv; o.w = O[i][3] * inv;
        *(float4*)(out + (size_t)(rowq + r0 + i) * 512 + h * 64 + c0) = o;
    }
}

// ---------------------------------------------------------------------------
// residual + layernorm (unchanged)
// ---------------------------------------------------------------------------
__global__ __launch_bounds__(256) void k_ln(const float* x, const float* r,
                                            const float* __restrict__ g,
                                            const float* __restrict__ b,
                                            float* out)
{
    int t = blockIdx.x, tid = threadIdx.x;
    size_t base = (size_t)t * DMODEL;
    float a0 = x[base + tid]       + r[base + tid];
    float a1 = x[base + tid + 256] + r[base + tid + 256];
    float s = a0 + a1;
    float q = fmaf(a0, a0, a1 * a1);
#pragma unroll
    for (int off = 32; off; off >>= 1) {
        s += __shfl_xor(s, off, 64);
        q += __shfl_xor(q, off, 64);
    }
    __shared__ float sw[8];
    int w = tid >> 6, lane = tid & 63;
    if (lane == 0) { sw[w] = s; sw[4 + w] = q; }
    __syncthreads();
    s = sw[0] + sw[1] + sw[2] + sw[3];
    q = sw[4] + sw[5] + sw[6] + sw[7];
    float mean = s * (1.0f / 512.0f);
    float var = q * (1.0f / 512.0f) - mean * mean;
    float inv = 1.0f / sqrtf(var + 1e-5f);
    out[base + tid]       = (a0 - mean) * inv * g[tid]       + b[tid];
    out[base + tid + 256] = (a1 - mean) * inv * g[tid + 256] + b[tid + 256];
}

// ---------------------------------------------------------------------------
// host side
// ---------------------------------------------------------------------------
static inline void launch_gemm(const float* A, const unsigned short* BH,
                               const unsigned short* BL, const float* bias,
                               float* C, int M, int N, int K, int relu,
                               hipStream_t stream)
{
    dim3 grid((N + 127) / 128, M / 128);
    k_gemm_mfma<<<grid, 256, 0, stream>>>(A, BH, BL, bias, C, M, N, K, relu);
}

extern "C" void kernel_launch(void* const* d_in, const int* in_sizes, int n_in,
                              void* d_out, int out_size, void* d_ws, size_t ws_size,
                              hipStream_t stream)
{
    (void)in_sizes; (void)n_in; (void)out_size;
    if (ws_size < WS_NEED) return;

    const int*   src = (const int*)  d_in[0];
    const float* emb = (const float*)d_in[1];
    const float* pos = (const float*)d_in[2];
    const float* ipw = (const float*)d_in[3];
    const float* ipb = (const float*)d_in[4];
    const float* opw = (const float*)d_in[5];
    const float* opb = (const float*)d_in[6];
    const float* ln1g = (const float*)d_in[7];
    const float* ln1b = (const float*)d_in[8];
    const float* ln2g = (const float*)d_in[9];
    const float* ln2b = (const float*)d_in[10];
    const float* w1  = (const float*)d_in[11];
    const float* bb1 = (const float*)d_in[12];
    const float* w2  = (const float*)d_in[13];
    const float* bb2 = (const float*)d_in[14];
    const float* ow  = (const float*)d_in[15];
    const float* ob  = (const float*)d_in[16];

    char* ws = (char*)d_ws;
    float* X   = (float*)(ws + X_B);
    float* Y   = (float*)(ws + Y_B);
    float* SHf = (float*)(ws + SH_B);                 // QKV / Z / F
    unsigned short* WH = (unsigned short*)(ws + WH_B);
    unsigned short* WL = (unsigned short*)(ws + WL_B);
    unsigned short* OWH = (unsigned short*)(ws + SH_B);                       // vocab splits
    unsigned short* OWL = (unsigned short*)(ws + SH_B + (size_t)VPAD * DMODEL * 2);
    unsigned int* HIST = (unsigned int*)(ws + HIST_B);
    PState* ST = (PState*)(ws + STATE_B);
    double* THR = (double*)(ws + THR_B);
    float* OUT = (float*)d_out;

    // embedding
    k_embed<<<MTOK, 256, 0, stream>>>(src, emb, pos, X);

    // prune thresholds for all 18 matrices (batched 3-level histogram select)
    k_prune_init<<<64, 256, 0, stream>>>(HIST, ST);
    for (int lev = 0; lev < 3; ++lev) {
        k_prune_hist<<<18 * 64, 256, 0, stream>>>(ipw, w1, w2, HIST, ST);
        k_prune_select<<<36, 256, 0, stream>>>(HIST, ST);
    }
    k_prune_capture<<<18 * 64, 256, 0, stream>>>(ipw, w1, w2, ST);
    k_prune_thr<<<1, 32, 0, stream>>>(ST, THR);

    for (int l = 0; l < NLAYER; ++l) {
        // qkv = x @ prune(in_proj_w)^T + b   -> SHf (QKV fp32 [8192][1536])
        k_apply_mask_split<<<1024, 256, 0, stream>>>(ipw + (size_t)l * 786432, WH, WL,
                                                     THR, 3 * l + 0, 786432);
        launch_gemm(X, WH, WL, ipb + (size_t)l * 1536, SHf, MTOK, 1536, DMODEL, 0, stream);
        // attention: SHf -> Y
        k_attn<<<dim3(128, 8), 256, 0, stream>>>(SHf, Y);
        // out projection (raw weights, split) : Y -> SHf (Z, over dead QKV)
        k_split<<<512, 256, 0, stream>>>(opw + (size_t)l * 262144, WH, WL, 262144, 262144);
        launch_gemm(Y, WH, WL, opb + (size_t)l * 512, SHf, MTOK, DMODEL, DMODEL, 0, stream);
        // x = LN(x + z)
        k_ln<<<MTOK, 256, 0, stream>>>(X, SHf, ln1g + (size_t)l * 512,
                                       ln1b + (size_t)l * 512, X);
        // ff1 = relu(x @ prune(lin1_w)^T + b)  -> SHf (F fp32 [8192][2048])
        k_apply_mask_split<<<1024, 256, 0, stream>>>(w1 + (size_t)l * 1048576, WH, WL,
                                                     THR, 3 * l + 1, 1048576);
        launch_gemm(X, WH, WL, bb1 + (size_t)l * 2048, SHf, MTOK, DFF, DMODEL, 1, stream);
        // ff2 = ff1 @ prune(lin2_w)^T + b  -> Y
        k_apply_mask_split<<<1024, 256, 0, stream>>>(w2 + (size_t)l * 1048576, WH, WL,
                                                     THR, 3 * l + 2, 1048576);
        launch_gemm(SHf, WH, WL, bb2 + (size_t)l * 512, Y, MTOK, DMODEL, DFF, 0, stream);
        // x = LN(x + ff)
        k_ln<<<MTOK, 256, 0, stream>>>(X, Y, ln2g + (size_t)l * 512,
                                       ln2b + (size_t)l * 512, X);
    }

    // logits = x @ out_w^T + out_b   (out_w split + zero-padded to 10112 rows)
    k_split<<<2048, 256, 0, stream>>>(ow, OWH, OWL, VOCAB * DMODEL, VPAD * DMODEL);
    launch_gemm(X, OWH, OWL, ob, OUT, MTOK, VOCAB, DMODEL, 0, stream);
}